// Round 3
// baseline (50.047 us; speedup 1.0000x reference)
//
#include <hip/hip_runtime.h>

typedef __bf16 bf16x8 __attribute__((ext_vector_type(8)));
typedef float f32x16 __attribute__((ext_vector_type(16)));
typedef float f32x4  __attribute__((ext_vector_type(4)));
typedef unsigned int u32x4 __attribute__((ext_vector_type(4)));

#define HEAD_DIM 128
#define D_MODEL  4096   // 32 heads * 128

// pack two floats into one u32 of 2x bf16 (RNE via __bf16 cast)
__device__ __forceinline__ unsigned pack_bf16(float lo, float hi) {
    unsigned a = (unsigned)__builtin_bit_cast(unsigned short, (__bf16)lo);
    unsigned b = (unsigned)__builtin_bit_cast(unsigned short, (__bf16)hi);
    return a | (b << 16);
}

// One QK^T K-step: load 16 f32 of Q and K (row r, cols hi*8+s*16..),
// convert to bf16 fragments, MFMA into acc (D[kv][h]).
__device__ __forceinline__ void qk_step(const float* __restrict__ qb,
                                        const float* __restrict__ kb,
                                        int rowoff, int s, f32x16& acc) {
    const float* qp = qb + rowoff + s * 16;
    const float* kp = kb + rowoff + s * 16;
    f32x4 q0 = *(const f32x4*)(qp);
    f32x4 q1 = *(const f32x4*)(qp + 4);
    f32x4 k0 = *(const f32x4*)(kp);
    f32x4 k1 = *(const f32x4*)(kp + 4);
    bf16x8 aK, bQ;
#pragma unroll
    for (int j = 0; j < 4; ++j) { aK[j] = (__bf16)k0[j]; aK[4 + j] = (__bf16)k1[j]; }
#pragma unroll
    for (int j = 0; j < 4; ++j) { bQ[j] = (__bf16)q0[j]; bQ[4 + j] = (__bf16)q1[j]; }
    acc = __builtin_amdgcn_mfma_f32_32x32x16_bf16(aK, bQ, acc, 0, 0, 0);
}

// One wave per batch row b. Per-b attention: Q,K,V are 32x128.
//   scores^T = mfma(A=K, B=Q) -> D[kv][h]: lane holds h = lane&31,
//   kv(reg) = (reg&3) + 8*(reg>>2) + 4*(lane>>5)
// V loads are issued in the MIDDLE of the QK MFMA chain (after s=1) so their
// HBM latency hides under the remaining 6 MFMA steps + softmax. Output uses
// nontemporal stores (no L2 write-allocate pollution / RFO); V uses
// nontemporal loads (single-use stream).
__global__ __launch_bounds__(256, 4) void attn_kernel(
    const float* __restrict__ q,
    const float* __restrict__ k,
    const float* __restrict__ v,
    float* __restrict__ out)
{
    constexpr float SCALE_LOG2E = 0.08838834764831845f * 1.4426950408889634f;

    const int lane = threadIdx.x & 63;
    const int b    = blockIdx.x * 4 + (threadIdx.x >> 6);
    const int r    = lane & 31;
    const int hi   = lane >> 5;

    const float* qb = q + (size_t)b * D_MODEL;
    const float* kb = k + (size_t)b * D_MODEL;
    const float* vb = v + (size_t)b * D_MODEL;

    const int rowoff = r * HEAD_DIM + hi * 8;

    // ---------- scores^T = K * Q^T : D[kv][h] ----------
    f32x16 acc = {};
    qk_step(qb, kb, rowoff, 0, acc);
    qk_step(qb, kb, rowoff, 1, acc);

    // ---------- issue ALL V loads now (independent of softmax; in flight
    // under the remaining 6 QK steps + softmax) ----------
    // vf[t*32 + c*8 + j] = V[t*16 + hi*8 + j][c*32 + r]
    float vf[64];
#pragma unroll
    for (int t = 0; t < 2; ++t)
#pragma unroll
        for (int c = 0; c < 4; ++c) {
            const float* vp = vb + (size_t)(t * 16 + hi * 8) * HEAD_DIM + c * 32 + r;
#pragma unroll
            for (int j = 0; j < 8; ++j)
                vf[t * 32 + c * 8 + j] = __builtin_nontemporal_load(vp + (size_t)j * HEAD_DIM);
        }

#pragma unroll
    for (int s = 2; s < 8; ++s) qk_step(qb, kb, rowoff, s, acc);

    // ---------- softmax over kv (h = r is lane-local), in place ----------
    float m = acc[0];
#pragma unroll
    for (int i = 1; i < 16; ++i) m = fmaxf(m, acc[i]);
    m = fmaxf(m, __shfl_xor(m, 32, 64));

    float sum = 0.f;
#pragma unroll
    for (int i = 0; i < 16; ++i) {
        acc[i] = __builtin_amdgcn_exp2f((acc[i] - m) * SCALE_LOG2E);
        sum += acc[i];
    }
    sum += __shfl_xor(sum, 32, 64);
    const float inv = __builtin_amdgcn_rcpf(sum);

    // ---------- repack into A-fragment of P^T[h][kv] ----------
    unsigned w[8];
#pragma unroll
    for (int i = 0; i < 8; ++i) w[i] = pack_bf16(acc[2 * i] * inv, acc[2 * i + 1] * inv);

    bf16x8 pa[2];
#pragma unroll
    for (int t = 0; t < 2; ++t) {
        unsigned W0 = w[4 * t], W1 = w[4 * t + 1], W2 = w[4 * t + 2], W3 = w[4 * t + 3];
        unsigned X0 = (unsigned)__shfl_xor((int)W0, 32, 64);
        unsigned X1 = (unsigned)__shfl_xor((int)W1, 32, 64);
        unsigned X2 = (unsigned)__shfl_xor((int)W2, 32, 64);
        unsigned X3 = (unsigned)__shfl_xor((int)W3, 32, 64);
        u32x4 wv;
        wv[0] = hi ? X2 : W0;
        wv[1] = hi ? X3 : W1;
        wv[2] = hi ? W2 : X0;
        wv[3] = hi ? W3 : X1;
        pa[t] = __builtin_bit_cast(bf16x8, wv);
    }

    // ---------- out[h][d] = P^T * V ----------
    float* ob = out + (size_t)b * D_MODEL;
#pragma unroll
    for (int c = 0; c < 4; ++c) {
        f32x16 oacc = {};
#pragma unroll
        for (int t = 0; t < 2; ++t) {
            bf16x8 bV;
#pragma unroll
            for (int j = 0; j < 8; ++j) bV[j] = (__bf16)vf[t * 32 + c * 8 + j];
            oacc = __builtin_amdgcn_mfma_f32_32x32x16_bf16(pa[t], bV, oacc, 0, 0, 0);
        }
        float* op = ob + c * 32 + r;
#pragma unroll
        for (int reg = 0; reg < 16; ++reg) {
            const int h = (reg & 3) + 8 * (reg >> 2) + 4 * hi;
            __builtin_nontemporal_store(oacc[reg], op + (size_t)h * HEAD_DIM);
        }
    }
}

extern "C" void kernel_launch(void* const* d_in, const int* in_sizes, int n_in,
                              void* d_out, int out_size, void* d_ws, size_t ws_size,
                              hipStream_t stream) {
    const float* q = (const float*)d_in[0];
    const float* k = (const float*)d_in[1];
    const float* v = (const float*)d_in[2];
    float* out = (float*)d_out;
    const int B = in_sizes[0] / D_MODEL;   // 4096
    attn_kernel<<<dim3(B / 4), dim3(256), 0, stream>>>(q, k, v, out);
}

// Round 4
// 46.007 us; speedup vs baseline: 1.0878x; 1.0878x over previous
//
#include <hip/hip_runtime.h>

typedef __bf16 bf16x8 __attribute__((ext_vector_type(8)));
typedef float f32x16 __attribute__((ext_vector_type(16)));
typedef float f32x4  __attribute__((ext_vector_type(4)));
typedef unsigned int u32x4 __attribute__((ext_vector_type(4)));

#define HEAD_DIM 128
#define D_MODEL  4096   // 32 heads * 128

// pack two floats into one u32 of 2x bf16 (RNE via __bf16 cast)
__device__ __forceinline__ unsigned pack_bf16(float lo, float hi) {
    unsigned a = (unsigned)__builtin_bit_cast(unsigned short, (__bf16)lo);
    unsigned b = (unsigned)__builtin_bit_cast(unsigned short, (__bf16)hi);
    return a | (b << 16);
}

// One wave per batch row b. Per-b attention: Q,K,V are 32x128.
//   scores^T = mfma(A=K, B=Q) -> D[kv][h]: lane holds h = lane&31,
//   kv(reg) = (reg&3) + 8*(reg>>2) + 4*(lane>>5)
// 4-deep explicit load pipeline: s=0..3 Q/K raws + all 64 V floats are in
// flight before the first MFMA consumes anything; each consumed slot is
// refilled with s+4's loads. launch_bounds(256,3) -> ~170 VGPR budget,
// 12 waves/CU, ~32KB outstanding per wave.
__global__ __launch_bounds__(256, 3) void attn_kernel(
    const float* __restrict__ q,
    const float* __restrict__ k,
    const float* __restrict__ v,
    float* __restrict__ out)
{
    constexpr float SCALE_LOG2E = 0.08838834764831845f * 1.4426950408889634f;

    const int lane = threadIdx.x & 63;
    const int b    = blockIdx.x * 4 + (threadIdx.x >> 6);
    const int r    = lane & 31;
    const int hi   = lane >> 5;

    const float* qb = q + (size_t)b * D_MODEL;
    const float* kb = k + (size_t)b * D_MODEL;
    const float* vb = v + (size_t)b * D_MODEL;

    const int rowoff = r * HEAD_DIM + hi * 8;

    // ---------- issue Q/K loads for s = 0..3 (4-deep pipeline fill) ----------
    f32x4 qr0[4], qr1[4], kr0[4], kr1[4];
#pragma unroll
    for (int s = 0; s < 4; ++s) {
        const float* qp = qb + rowoff + s * 16;
        const float* kp = kb + rowoff + s * 16;
        qr0[s] = *(const f32x4*)(qp);
        qr1[s] = *(const f32x4*)(qp + 4);
        kr0[s] = *(const f32x4*)(kp);
        kr1[s] = *(const f32x4*)(kp + 4);
    }

    // ---------- issue ALL V loads (independent of softmax) ----------
    // vf[t*32 + c*8 + j] = V[t*16 + hi*8 + j][c*32 + r]
    float vf[64];
#pragma unroll
    for (int t = 0; t < 2; ++t)
#pragma unroll
        for (int c = 0; c < 4; ++c) {
            const float* vp = vb + (size_t)(t * 16 + hi * 8) * HEAD_DIM + c * 32 + r;
#pragma unroll
            for (int j = 0; j < 8; ++j)
                vf[t * 32 + c * 8 + j] = vp[(size_t)j * HEAD_DIM];
        }

    // ---------- scores^T = K * Q^T : D[kv][h], refilling slots ----------
    f32x16 acc = {};
#pragma unroll
    for (int s = 0; s < 8; ++s) {
        const int slot = s & 3;
        bf16x8 aK, bQ;
#pragma unroll
        for (int j = 0; j < 4; ++j) { aK[j] = (__bf16)kr0[slot][j]; aK[4 + j] = (__bf16)kr1[slot][j]; }
#pragma unroll
        for (int j = 0; j < 4; ++j) { bQ[j] = (__bf16)qr0[slot][j]; bQ[4 + j] = (__bf16)qr1[slot][j]; }
        if (s + 4 < 8) {
            const float* qp = qb + rowoff + (s + 4) * 16;
            const float* kp = kb + rowoff + (s + 4) * 16;
            qr0[slot] = *(const f32x4*)(qp);
            qr1[slot] = *(const f32x4*)(qp + 4);
            kr0[slot] = *(const f32x4*)(kp);
            kr1[slot] = *(const f32x4*)(kp + 4);
        }
        acc = __builtin_amdgcn_mfma_f32_32x32x16_bf16(aK, bQ, acc, 0, 0, 0);
    }

    // ---------- softmax over kv (h = r is lane-local), in place ----------
    float m = acc[0];
#pragma unroll
    for (int i = 1; i < 16; ++i) m = fmaxf(m, acc[i]);
    m = fmaxf(m, __shfl_xor(m, 32, 64));

    float sum = 0.f;
#pragma unroll
    for (int i = 0; i < 16; ++i) {
        acc[i] = __builtin_amdgcn_exp2f((acc[i] - m) * SCALE_LOG2E);
        sum += acc[i];
    }
    sum += __shfl_xor(sum, 32, 64);
    const float inv = __builtin_amdgcn_rcpf(sum);

    // ---------- repack into A-fragment of P^T[h][kv] ----------
    unsigned w[8];
#pragma unroll
    for (int i = 0; i < 8; ++i) w[i] = pack_bf16(acc[2 * i] * inv, acc[2 * i + 1] * inv);

    bf16x8 pa[2];
#pragma unroll
    for (int t = 0; t < 2; ++t) {
        unsigned W0 = w[4 * t], W1 = w[4 * t + 1], W2 = w[4 * t + 2], W3 = w[4 * t + 3];
        unsigned X0 = (unsigned)__shfl_xor((int)W0, 32, 64);
        unsigned X1 = (unsigned)__shfl_xor((int)W1, 32, 64);
        unsigned X2 = (unsigned)__shfl_xor((int)W2, 32, 64);
        unsigned X3 = (unsigned)__shfl_xor((int)W3, 32, 64);
        u32x4 wv;
        wv[0] = hi ? X2 : W0;
        wv[1] = hi ? X3 : W1;
        wv[2] = hi ? W2 : X0;
        wv[3] = hi ? W3 : X1;
        pa[t] = __builtin_bit_cast(bf16x8, wv);
    }

    // ---------- out[h][d] = P^T * V ----------
    float* ob = out + (size_t)b * D_MODEL;
#pragma unroll
    for (int c = 0; c < 4; ++c) {
        f32x16 oacc = {};
#pragma unroll
        for (int t = 0; t < 2; ++t) {
            bf16x8 bV;
#pragma unroll
            for (int j = 0; j < 8; ++j) bV[j] = (__bf16)vf[t * 32 + c * 8 + j];
            oacc = __builtin_amdgcn_mfma_f32_32x32x16_bf16(pa[t], bV, oacc, 0, 0, 0);
        }
        float* op = ob + c * 32 + r;
#pragma unroll
        for (int reg = 0; reg < 16; ++reg) {
            const int h = (reg & 3) + 8 * (reg >> 2) + 4 * hi;
            op[(size_t)h * HEAD_DIM] = oacc[reg];
        }
    }
}

extern "C" void kernel_launch(void* const* d_in, const int* in_sizes, int n_in,
                              void* d_out, int out_size, void* d_ws, size_t ws_size,
                              hipStream_t stream) {
    const float* q = (const float*)d_in[0];
    const float* k = (const float*)d_in[1];
    const float* v = (const float*)d_in[2];
    float* out = (float*)d_out;
    const int B = in_sizes[0] / D_MODEL;   // 4096
    attn_kernel<<<dim3(B / 4), dim3(256), 0, stream>>>(q, k, v, out);
}

// Round 5
// 44.652 us; speedup vs baseline: 1.1208x; 1.0304x over previous
//
#include <hip/hip_runtime.h>

typedef __bf16 bf16x8 __attribute__((ext_vector_type(8)));
typedef float f32x16 __attribute__((ext_vector_type(16)));
typedef float f32x4  __attribute__((ext_vector_type(4)));
typedef unsigned int u32x2 __attribute__((ext_vector_type(2)));
typedef unsigned int u32x4 __attribute__((ext_vector_type(4)));

#define HEAD_DIM 128
#define D_MODEL  4096   // 32 heads * 128

// pack two floats into one u32 of 2x bf16 (RNE via __bf16 cast)
__device__ __forceinline__ unsigned pack_bf16(float lo, float hi) {
    unsigned a = (unsigned)__builtin_bit_cast(unsigned short, (__bf16)lo);
    unsigned b = (unsigned)__builtin_bit_cast(unsigned short, (__bf16)hi);
    return a | (b << 16);
}

// One wave per batch row b. Q,K are loaded with PERFECTLY CONTIGUOUS
// dwordx4 (full 128B-line requests), converted to bf16, staged in a
// per-wave-private LDS slice (no barriers needed), and fragment-read with
// an XOR row-swizzle. V loads / output stores already issue full 128B
// segments and stay in registers / direct stores.
//   scores^T = mfma(A=K, B=Q) -> D[kv][h]: lane holds h = lane&31,
//   kv(reg) = (reg&3) + 8*(reg>>2) + 4*(lane>>5)
__global__ __launch_bounds__(256, 2) void attn_kernel(
    const float* __restrict__ q,
    const float* __restrict__ k,
    const float* __restrict__ v,
    float* __restrict__ out)
{
    constexpr float SCALE_LOG2E = 0.08838834764831845f * 1.4426950408889634f;

    __shared__ u32x4 lds_buf[4096];   // 64 KB: 4 waves x (Q 8KB + K 8KB) bf16
    const int wid  = threadIdx.x >> 6;
    const int lane = threadIdx.x & 63;
    char* ldsQ = (char*)lds_buf + wid * 16384;
    char* ldsK = ldsQ + 8192;

    const int b  = blockIdx.x * 4 + wid;
    const int r  = lane & 31;
    const int hi = lane >> 5;

    const float* qb = q + (size_t)b * D_MODEL;
    const float* kb = k + (size_t)b * D_MODEL;
    const float* vb = v + (size_t)b * D_MODEL;

    // ---- 1. contiguous Q loads: instr i covers f32 elems [i*256+lane*4,+4)
    f32x4 qraw[16];
#pragma unroll
    for (int i = 0; i < 16; ++i)
        qraw[i] = *(const f32x4*)(qb + i * 256 + lane * 4);

    // ---- 2. all V loads (full 128B segments; register-resident to PV)
    // vf[t*32 + c*8 + j] = V[t*16 + hi*8 + j][c*32 + r]
    float vf[64];
#pragma unroll
    for (int t = 0; t < 2; ++t)
#pragma unroll
        for (int c = 0; c < 4; ++c) {
            const float* vp = vb + (size_t)(t * 16 + hi * 8) * HEAD_DIM + c * 32 + r;
#pragma unroll
            for (int j = 0; j < 8; ++j)
                vf[t * 32 + c * 8 + j] = vp[(size_t)j * HEAD_DIM];
        }

    // ---- 3. convert Q -> bf16, store to LDS with XOR row-swizzle
    // logical bf16 byte = i*512 + lane*8 ; row = byte>>8 ; swz ^= (row&7)<<4
#pragma unroll
    for (int i = 0; i < 16; ++i) {
        const int byteoff = i * 512 + lane * 8;
        const int row = byteoff >> 8;
        const int swz = byteoff ^ ((row & 7) << 4);
        u32x2 w2;
        w2[0] = pack_bf16(qraw[i][0], qraw[i][1]);
        w2[1] = pack_bf16(qraw[i][2], qraw[i][3]);
        *(u32x2*)(ldsQ + swz) = w2;
    }

    // ---- 4. contiguous K loads
    f32x4 kraw[16];
#pragma unroll
    for (int i = 0; i < 16; ++i)
        kraw[i] = *(const f32x4*)(kb + i * 256 + lane * 4);

    // ---- 5. convert K -> bf16, store to LDS
#pragma unroll
    for (int i = 0; i < 16; ++i) {
        const int byteoff = i * 512 + lane * 8;
        const int row = byteoff >> 8;
        const int swz = byteoff ^ ((row & 7) << 4);
        u32x2 w2;
        w2[0] = pack_bf16(kraw[i][0], kraw[i][1]);
        w2[1] = pack_bf16(kraw[i][2], kraw[i][3]);
        *(u32x2*)(ldsK + swz) = w2;
    }

    // ---- 6. fragment reads (ds_read_b128, swizzled) + QK^T MFMA chain
    // lane (r,hi) step s reads 8 bf16 at d = s*16 + hi*8  (same as prior
    // passing kernel: byte = r*256 + s*32 + hi*16)
    f32x16 acc = {};
#pragma unroll
    for (int s = 0; s < 8; ++s) {
        const int fb   = r * 256 + s * 32 + hi * 16;
        const int fswz = fb ^ ((r & 7) << 4);
        bf16x8 aK = *(const bf16x8*)(ldsK + fswz);
        bf16x8 bQ = *(const bf16x8*)(ldsQ + fswz);
        acc = __builtin_amdgcn_mfma_f32_32x32x16_bf16(aK, bQ, acc, 0, 0, 0);
    }

    // ---- 7. softmax over kv (h = r is lane-local), in place
    float m = acc[0];
#pragma unroll
    for (int i = 1; i < 16; ++i) m = fmaxf(m, acc[i]);
    m = fmaxf(m, __shfl_xor(m, 32, 64));

    float sum = 0.f;
#pragma unroll
    for (int i = 0; i < 16; ++i) {
        acc[i] = __builtin_amdgcn_exp2f((acc[i] - m) * SCALE_LOG2E);
        sum += acc[i];
    }
    sum += __shfl_xor(sum, 32, 64);
    const float inv = __builtin_amdgcn_rcpf(sum);

    // ---- 8. repack into A-fragment of P^T[h][kv]
    unsigned w[8];
#pragma unroll
    for (int i = 0; i < 8; ++i) w[i] = pack_bf16(acc[2 * i] * inv, acc[2 * i + 1] * inv);

    bf16x8 pa[2];
#pragma unroll
    for (int t = 0; t < 2; ++t) {
        unsigned W0 = w[4 * t], W1 = w[4 * t + 1], W2 = w[4 * t + 2], W3 = w[4 * t + 3];
        unsigned X0 = (unsigned)__shfl_xor((int)W0, 32, 64);
        unsigned X1 = (unsigned)__shfl_xor((int)W1, 32, 64);
        unsigned X2 = (unsigned)__shfl_xor((int)W2, 32, 64);
        unsigned X3 = (unsigned)__shfl_xor((int)W3, 32, 64);
        u32x4 wv;
        wv[0] = hi ? X2 : W0;
        wv[1] = hi ? X3 : W1;
        wv[2] = hi ? W2 : X0;
        wv[3] = hi ? W3 : X1;
        pa[t] = __builtin_bit_cast(bf16x8, wv);
    }

    // ---- 9. out[h][d] = P^T * V
    float* ob = out + (size_t)b * D_MODEL;
#pragma unroll
    for (int c = 0; c < 4; ++c) {
        f32x16 oacc = {};
#pragma unroll
        for (int t = 0; t < 2; ++t) {
            bf16x8 bV;
#pragma unroll
            for (int j = 0; j < 8; ++j) bV[j] = (__bf16)vf[t * 32 + c * 8 + j];
            oacc = __builtin_amdgcn_mfma_f32_32x32x16_bf16(pa[t], bV, oacc, 0, 0, 0);
        }
        float* op = ob + c * 32 + r;
#pragma unroll
        for (int reg = 0; reg < 16; ++reg) {
            const int h = (reg & 3) + 8 * (reg >> 2) + 4 * hi;
            op[(size_t)h * HEAD_DIM] = oacc[reg];
        }
    }
}

extern "C" void kernel_launch(void* const* d_in, const int* in_sizes, int n_in,
                              void* d_out, int out_size, void* d_ws, size_t ws_size,
                              hipStream_t stream) {
    const float* q = (const float*)d_in[0];
    const float* k = (const float*)d_in[1];
    const float* v = (const float*)d_in[2];
    float* out = (float*)d_out;
    const int B = in_sizes[0] / D_MODEL;   // 4096
    attn_kernel<<<dim3(B / 4), dim3(256), 0, stream>>>(q, k, v, out);
}

// Round 6
// 44.176 us; speedup vs baseline: 1.1329x; 1.0108x over previous
//
#include <hip/hip_runtime.h>

typedef __bf16 bf16x8 __attribute__((ext_vector_type(8)));
typedef float f32x16 __attribute__((ext_vector_type(16)));
typedef float f32x4  __attribute__((ext_vector_type(4)));
typedef unsigned int u32x2 __attribute__((ext_vector_type(2)));
typedef unsigned int u32x4 __attribute__((ext_vector_type(4)));

#define HEAD_DIM 128
#define D_MODEL  4096   // 32 heads * 128

// pack two floats into one u32 of 2x bf16 (RNE via __bf16 cast)
__device__ __forceinline__ unsigned pack_bf16(float lo, float hi) {
    unsigned a = (unsigned)__builtin_bit_cast(unsigned short, (__bf16)lo);
    unsigned b = (unsigned)__builtin_bit_cast(unsigned short, (__bf16)hi);
    return a | (b << 16);
}

// ONE WAVE PER BLOCK, one block per batch row b. 16KB LDS/block -> up to 10
// independent workgroups/CU, each at its own load/compute phase (no lockstep,
// per-wave retirement keeps the memory pipe fed). No barriers: LDS is
// same-wave coherent via lgkmcnt.
// Q,K: contiguous dwordx4 loads (full-line requests) -> bf16 -> LDS with XOR
// row-swizzle; fragments read as swizzled ds_read_b128.
//   scores^T = mfma(A=K, B=Q) -> D[kv][h]: lane holds h = lane&31,
//   kv(reg) = (reg&3) + 8*(reg>>2) + 4*(lane>>5)
__global__ __launch_bounds__(64, 4) void attn_kernel(
    const float* __restrict__ q,
    const float* __restrict__ k,
    const float* __restrict__ v,
    float* __restrict__ out)
{
    constexpr float SCALE_LOG2E = 0.08838834764831845f * 1.4426950408889634f;

    __shared__ char lds[16384];     // Q bf16 8KB + K bf16 8KB
    char* ldsQ = lds;
    char* ldsK = lds + 8192;

    const int lane = threadIdx.x;   // 0..63
    const int b  = blockIdx.x;
    const int r  = lane & 31;
    const int hi = lane >> 5;

    const float* qb = q + (size_t)b * D_MODEL;
    const float* kb = k + (size_t)b * D_MODEL;
    const float* vb = v + (size_t)b * D_MODEL;

    // ---- 1. Q: contiguous loads -> bf16 -> LDS (XOR row-swizzle)
    {
        f32x4 qraw[16];
#pragma unroll
        for (int i = 0; i < 16; ++i)
            qraw[i] = *(const f32x4*)(qb + i * 256 + lane * 4);
#pragma unroll
        for (int i = 0; i < 16; ++i) {
            const int byteoff = i * 512 + lane * 8;
            const int row = byteoff >> 8;
            const int swz = byteoff ^ ((row & 7) << 4);
            u32x2 w2;
            w2[0] = pack_bf16(qraw[i][0], qraw[i][1]);
            w2[1] = pack_bf16(qraw[i][2], qraw[i][3]);
            *(u32x2*)(ldsQ + swz) = w2;
        }
    }

    // ---- 2. K: contiguous loads -> bf16 -> LDS
    {
        f32x4 kraw[16];
#pragma unroll
        for (int i = 0; i < 16; ++i)
            kraw[i] = *(const f32x4*)(kb + i * 256 + lane * 4);
#pragma unroll
        for (int i = 0; i < 16; ++i) {
            const int byteoff = i * 512 + lane * 8;
            const int row = byteoff >> 8;
            const int swz = byteoff ^ ((row & 7) << 4);
            u32x2 w2;
            w2[0] = pack_bf16(kraw[i][0], kraw[i][1]);
            w2[1] = pack_bf16(kraw[i][2], kraw[i][3]);
            *(u32x2*)(ldsK + swz) = w2;
        }
    }

    // ---- 3. V loads (full 128B segments; latency hides under MFMA+softmax)
    // vf[t*32 + c*8 + j] = V[t*16 + hi*8 + j][c*32 + r]
    float vf[64];
#pragma unroll
    for (int t = 0; t < 2; ++t)
#pragma unroll
        for (int c = 0; c < 4; ++c) {
            const float* vp = vb + (size_t)(t * 16 + hi * 8) * HEAD_DIM + c * 32 + r;
#pragma unroll
            for (int j = 0; j < 8; ++j)
                vf[t * 32 + c * 8 + j] = vp[(size_t)j * HEAD_DIM];
        }

    // ---- 4. QK^T MFMA chain from LDS fragments
    f32x16 acc = {};
#pragma unroll
    for (int s = 0; s < 8; ++s) {
        const int fb   = r * 256 + s * 32 + hi * 16;
        const int fswz = fb ^ ((r & 7) << 4);
        bf16x8 aK = *(const bf16x8*)(ldsK + fswz);
        bf16x8 bQ = *(const bf16x8*)(ldsQ + fswz);
        acc = __builtin_amdgcn_mfma_f32_32x32x16_bf16(aK, bQ, acc, 0, 0, 0);
    }

    // ---- 5. softmax over kv (h = r is lane-local), in place
    float m = acc[0];
#pragma unroll
    for (int i = 1; i < 16; ++i) m = fmaxf(m, acc[i]);
    m = fmaxf(m, __shfl_xor(m, 32, 64));

    float sum = 0.f;
#pragma unroll
    for (int i = 0; i < 16; ++i) {
        acc[i] = __builtin_amdgcn_exp2f((acc[i] - m) * SCALE_LOG2E);
        sum += acc[i];
    }
    sum += __shfl_xor(sum, 32, 64);
    const float inv = __builtin_amdgcn_rcpf(sum);

    // ---- 6. repack into A-fragment of P^T[h][kv]
    unsigned w[8];
#pragma unroll
    for (int i = 0; i < 8; ++i) w[i] = pack_bf16(acc[2 * i] * inv, acc[2 * i + 1] * inv);

    bf16x8 pa[2];
#pragma unroll
    for (int t = 0; t < 2; ++t) {
        unsigned W0 = w[4 * t], W1 = w[4 * t + 1], W2 = w[4 * t + 2], W3 = w[4 * t + 3];
        unsigned X0 = (unsigned)__shfl_xor((int)W0, 32, 64);
        unsigned X1 = (unsigned)__shfl_xor((int)W1, 32, 64);
        unsigned X2 = (unsigned)__shfl_xor((int)W2, 32, 64);
        unsigned X3 = (unsigned)__shfl_xor((int)W3, 32, 64);
        u32x4 wv;
        wv[0] = hi ? X2 : W0;
        wv[1] = hi ? X3 : W1;
        wv[2] = hi ? W2 : X0;
        wv[3] = hi ? W3 : X1;
        pa[t] = __builtin_bit_cast(bf16x8, wv);
    }

    // ---- 7. out[h][d] = P^T * V
    float* ob = out + (size_t)b * D_MODEL;
#pragma unroll
    for (int c = 0; c < 4; ++c) {
        f32x16 oacc = {};
#pragma unroll
        for (int t = 0; t < 2; ++t) {
            bf16x8 bV;
#pragma unroll
            for (int j = 0; j < 8; ++j) bV[j] = (__bf16)vf[t * 32 + c * 8 + j];
            oacc = __builtin_amdgcn_mfma_f32_32x32x16_bf16(pa[t], bV, oacc, 0, 0, 0);
        }
        float* op = ob + c * 32 + r;
#pragma unroll
        for (int reg = 0; reg < 16; ++reg) {
            const int h = (reg & 3) + 8 * (reg >> 2) + 4 * hi;
            op[(size_t)h * HEAD_DIM] = oacc[reg];
        }
    }
}

extern "C" void kernel_launch(void* const* d_in, const int* in_sizes, int n_in,
                              void* d_out, int out_size, void* d_ws, size_t ws_size,
                              hipStream_t stream) {
    const float* q = (const float*)d_in[0];
    const float* k = (const float*)d_in[1];
    const float* v = (const float*)d_in[2];
    float* out = (float*)d_out;
    const int B = in_sizes[0] / D_MODEL;   // 4096
    attn_kernel<<<dim3(B), dim3(64), 0, stream>>>(q, k, v, out);
}